// Round 6
// baseline (564.254 us; speedup 1.0000x reference)
//
#include <hip/hip_runtime.h>

// B=16384, N=54, D_IN=64, D_HID=4, D_OUT=256
// R2 structure (interleaved FC, double-buffered h through LDS) with:
//  - barriers batched: SUB=3 positions per barrier group (10 barriers/block
//    instead of 54) -> global loads pipeline across a 3x window
//  - Wf pre-transposed to WfT[54][256] float4 -> FC reads fully coalesced
//  - low register pressure: 1 position in flight per sub-iter
//
// Block 256 = 16 groups x 16 lanes; group g -> (row r=g>>1, col-half nh=g&1).
// Outer o (9 iters): compute 3 positions/group -> hbuf[o&1][sub][g]; barrier;
// FC: thread tid = output col, reads 6 coalesced WfT float4 + 48 broadcast
// h reads, accumulates acc2[8]. Hazard: writes to hbuf[p] recur at outer o+2,
// after barrier o+1 which orders all FC-o reads. Single-barrier-per-outer safe.

#define N_POS   54
#define D_OUT   256
#define THREADS 256
#define RB      8
#define SUB     3
#define OUTER   9          // SUB*OUTER = 27 = N_POS/2

__global__ void transpose_wf_kernel(const float* __restrict__ Wf,
                                    float4* __restrict__ WfT)
{
    const int col = threadIdx.x;       // 0..255
    const int n   = blockIdx.x;        // 0..53
    const float4* Wf4 = (const float4*)Wf;     // [256][54]
    WfT[n * 256 + col] = Wf4[col * 54 + n];
}

#define DOT(D, W) ((D).x*(W).x + (D).y*(W).y + (D).z*(W).z + (D).w*(W).w)

__global__ __launch_bounds__(THREADS, 4)
void hexconv_fc_kernel(const float* __restrict__ x,
                       const float* __restrict__ nb,
                       const float* __restrict__ Wc,
                       const float* __restrict__ bc,
                       const float* __restrict__ Wd,
                       const float* __restrict__ bd,
                       const float* __restrict__ bf,
                       const float4* __restrict__ WfT,
                       float* __restrict__ out)
{
    // combined weights: wlds4[hh*112 + t + 16*j]; j=0 -> Wc, j>=1 -> Wd[j-1]
    __shared__ float4 wlds4[4 * 112];        // 7168 B
    __shared__ float4 hbuf[2][SUB][16];      // 1536 B

    const int tid = threadIdx.x;

    const float4* Wc4 = (const float4*)Wc;   // [4][16]
    const float4* Wd4 = (const float4*)Wd;   // [6][4][16]
    for (int idx = tid; idx < 4 * 112; idx += THREADS) {
        const int hh = idx / 112;
        const int f  = idx - hh * 112;
        float4 v;
        if (f < 16) {
            v = Wc4[hh * 16 + f];
        } else {
            const int k  = (f - 16) >> 4;
            const int d4 = (f - 16) & 15;
            v = Wd4[(k * 4 + hh) * 16 + d4];
        }
        wlds4[idx] = v;
    }

    // bias: bc[hh] + sum_k bd[k][hh]
    float bias[4];
#pragma unroll
    for (int hh = 0; hh < 4; ++hh) {
        float s = bc[hh];
#pragma unroll
        for (int k = 0; k < 6; ++k) s += bd[k * 4 + hh];
        bias[hh] = s;
    }

    const int g  = tid >> 4;      // group 0..15
    const int t  = tid & 15;      // lane in group
    const int r  = g >> 1;        // batch row within block 0..7
    const int nh = g & 1;         // column half

    const int b0 = blockIdx.x * RB;
    const size_t rowBase = (size_t)(b0 + r) * N_POS;

    const float4* x4  = (const float4*)x;    // [pos][16]
    const float4* nb4 = (const float4*)nb;   // [pos][96]

    float acc2[RB];
#pragma unroll
    for (int r2 = 0; r2 < RB; ++r2) acc2[r2] = 0.f;

    __syncthreads();

    for (int o = 0; o < OUTER; ++o) {
        const int cur = o & 1;

        // ---- compute SUB positions for this group ----
#pragma unroll
        for (int sIt = 0; sIt < SUB; ++sIt) {
            const int it = o * SUB + sIt;
            const int n  = 2 * it + nh;
            const size_t p = rowBase + n;
            const float4* xp  = x4  + p * 16 + t;
            const float4* nbp = nb4 + p * 96 + t;

            const float4 d0 = xp[0];
            const float4 d1 = nbp[0];
            const float4 d2 = nbp[16];
            const float4 d3 = nbp[32];
            const float4 d4 = nbp[48];
            const float4 d5 = nbp[64];
            const float4 d6 = nbp[80];

            float a0 = 0.f, a1 = 0.f, a2 = 0.f, a3 = 0.f;
#define HEX(D, J) do {                                                         \
            float4 w_;                                                         \
            w_ = wlds4[0*112 + t + 16*(J)]; a0 += DOT(D, w_);                  \
            w_ = wlds4[1*112 + t + 16*(J)]; a1 += DOT(D, w_);                  \
            w_ = wlds4[2*112 + t + 16*(J)]; a2 += DOT(D, w_);                  \
            w_ = wlds4[3*112 + t + 16*(J)]; a3 += DOT(D, w_);                  \
        } while (0)
            HEX(d0, 0); HEX(d1, 1); HEX(d2, 2); HEX(d3, 3);
            HEX(d4, 4); HEX(d5, 5); HEX(d6, 6);
#undef HEX

#pragma unroll
            for (int m = 1; m <= 8; m <<= 1) {
                a0 += __shfl_xor(a0, m, 64);
                a1 += __shfl_xor(a1, m, 64);
                a2 += __shfl_xor(a2, m, 64);
                a3 += __shfl_xor(a3, m, 64);
            }

            if (t < 4) {
                const float av = (t == 0) ? a0 : (t == 1) ? a1 : (t == 2) ? a2 : a3;
                const float v = av + bias[t];
                ((float*)&hbuf[cur][sIt][g])[t] = v > 0.f ? v : 0.f;
            }
        }

        __syncthreads();

        // ---- FC: thread tid = output column; 6 columns this outer ----
#pragma unroll
        for (int sIt = 0; sIt < SUB; ++sIt) {
            const int it = o * SUB + sIt;
            const float4 w0 = WfT[(2 * it) * 256 + tid];       // coalesced
            const float4 w1 = WfT[(2 * it + 1) * 256 + tid];
#pragma unroll
            for (int g2 = 0; g2 < 16; ++g2) {
                const float4 hv = hbuf[cur][sIt][g2];
                const float4 w  = (g2 & 1) ? w1 : w0;
                acc2[g2 >> 1] += DOT(hv, w);
            }
        }
    }

    const float bfv = bf[tid];
    const size_t outBase = (size_t)b0 * D_OUT + tid;
#pragma unroll
    for (int r2 = 0; r2 < RB; ++r2)
        out[outBase + (size_t)r2 * D_OUT] = acc2[r2] + bfv;
}

extern "C" void kernel_launch(void* const* d_in, const int* in_sizes, int n_in,
                              void* d_out, int out_size, void* d_ws, size_t ws_size,
                              hipStream_t stream) {
    const float* x  = (const float*)d_in[0];
    const float* nb = (const float*)d_in[1];
    const float* Wc = (const float*)d_in[2];
    const float* bc = (const float*)d_in[3];
    const float* Wd = (const float*)d_in[4];
    const float* bd = (const float*)d_in[5];
    const float* Wf = (const float*)d_in[6];
    const float* bf = (const float*)d_in[7];
    float* out = (float*)d_out;

    const int B = 16384;
    float4* WfT = (float4*)d_ws;   // 221184 B, ws is preallocated scratch

    transpose_wf_kernel<<<dim3(N_POS), dim3(256), 0, stream>>>(Wf, WfT);

    dim3 grid(B / RB), block(THREADS);
    hexconv_fc_kernel<<<grid, block, 0, stream>>>(
        x, nb, Wc, bc, Wd, bd, bf, WfT, out);
}

// Round 8
// 272.001 us; speedup vs baseline: 2.0745x; 2.0745x over previous
//
#include <hip/hip_runtime.h>

// B=16384, N=54, D_IN=64, D_HID=4, D_OUT=256
// R2 structure (proven best: 307us), register-minimal, with:
//  - grid 2048 (RB=8) -> up to 8 blocks/CU at VGPR<=64; per-block barrier
//    drains overlap across 8 independent blocks per CU
//  - Wf pre-transposed to WfT[54][256] float4 -> FC reads fully coalesced
//  - nontemporal loads for the read-once x/nb streams (keep WfT L2-hot)
//
// Block 256 = 16 groups x 16 lanes; group g -> (row r=g>>1, col-half nh=g&1).
// Per iter: group computes one position's h[0..3] (7 float4 loads, dot vs LDS
// weights, 16-lane xor-butterfly), writes float4 to double-buffered hbuf,
// ONE barrier, then every thread (=output col) accumulates acc2[8] from the
// 16 fresh (row,col) pairs. Double-buffer + 1 barrier/iter is hazard-safe
// (write to buf recurs at it+2, ordered by barrier it+1).

#define N_POS   54
#define D_OUT   256
#define THREADS 256
#define RB      8
#define ITERS   27

typedef float f32x4 __attribute__((ext_vector_type(4)));

__global__ void transpose_wf_kernel(const float* __restrict__ Wf,
                                    float4* __restrict__ WfT)
{
    const int col = threadIdx.x;       // 0..255
    const int n   = blockIdx.x;        // 0..53
    const float4* Wf4 = (const float4*)Wf;     // [256][54]
    WfT[n * 256 + col] = Wf4[col * 54 + n];
}

#define DOT(D, W) ((D).x*(W).x + (D).y*(W).y + (D).z*(W).z + (D).w*(W).w)
#define DOTV(D, W) ((D)[0]*(W).x + (D)[1]*(W).y + (D)[2]*(W).z + (D)[3]*(W).w)
#define NTL(P)    __builtin_nontemporal_load((const f32x4*)(P))

__global__ __launch_bounds__(THREADS, 4)
void hexconv_fc_kernel(const float* __restrict__ x,
                       const float* __restrict__ nb,
                       const float* __restrict__ Wc,
                       const float* __restrict__ bc,
                       const float* __restrict__ Wd,
                       const float* __restrict__ bd,
                       const float* __restrict__ bf,
                       const float4* __restrict__ WfT,
                       float* __restrict__ out)
{
    // combined weights: wlds4[hh*112 + t + 16*j]; j=0 -> Wc, j>=1 -> Wd[j-1]
    __shared__ float4 wlds4[4 * 112];   // 7168 B
    __shared__ float4 hbuf[2][16];      // 512 B

    const int tid = threadIdx.x;

    const float4* Wc4 = (const float4*)Wc;   // [4][16]
    const float4* Wd4 = (const float4*)Wd;   // [6][4][16]
    for (int idx = tid; idx < 4 * 112; idx += THREADS) {
        const int hh = idx / 112;
        const int f  = idx - hh * 112;
        float4 v;
        if (f < 16) {
            v = Wc4[hh * 16 + f];
        } else {
            const int k  = (f - 16) >> 4;
            const int d4 = (f - 16) & 15;
            v = Wd4[(k * 4 + hh) * 16 + d4];
        }
        wlds4[idx] = v;
    }

    // bias: bc[hh] + sum_k bd[k][hh] (named scalars)
    float bias0 = bc[0], bias1 = bc[1], bias2 = bc[2], bias3 = bc[3];
#pragma unroll
    for (int k = 0; k < 6; ++k) {
        bias0 += bd[k * 4 + 0];
        bias1 += bd[k * 4 + 1];
        bias2 += bd[k * 4 + 2];
        bias3 += bd[k * 4 + 3];
    }

    const int g  = tid >> 4;      // group 0..15
    const int t  = tid & 15;      // lane in group
    const int r  = g >> 1;        // batch row within block 0..7
    const int nh = g & 1;         // column half

    const int b0 = blockIdx.x * RB;
    const size_t rowBase = (size_t)(b0 + r) * N_POS;

    const float4* x4  = (const float4*)x;    // [pos][16]
    const float4* nb4 = (const float4*)nb;   // [pos][96]

    float acc2[RB];
#pragma unroll
    for (int r2 = 0; r2 < RB; ++r2) acc2[r2] = 0.f;

    __syncthreads();

    for (int it = 0; it < ITERS; ++it) {
        const int n = 2 * it + nh;
        const size_t p = rowBase + n;
        const float4* xp  = x4  + p * 16 + t;
        const float4* nbp = nb4 + p * 96 + t;

        const f32x4 d0 = NTL(xp);
        const f32x4 d1 = NTL(nbp);
        const f32x4 d2 = NTL(nbp + 16);
        const f32x4 d3 = NTL(nbp + 32);
        const f32x4 d4 = NTL(nbp + 48);
        const f32x4 d5 = NTL(nbp + 64);
        const f32x4 d6 = NTL(nbp + 80);

        float a0 = 0.f, a1 = 0.f, a2 = 0.f, a3 = 0.f;
#define HEX(D, J) do {                                                         \
        float4 w_;                                                             \
        w_ = wlds4[0*112 + t + 16*(J)]; a0 += DOTV(D, w_);                     \
        w_ = wlds4[1*112 + t + 16*(J)]; a1 += DOTV(D, w_);                     \
        w_ = wlds4[2*112 + t + 16*(J)]; a2 += DOTV(D, w_);                     \
        w_ = wlds4[3*112 + t + 16*(J)]; a3 += DOTV(D, w_);                     \
    } while (0)
        HEX(d0, 0); HEX(d1, 1); HEX(d2, 2); HEX(d3, 3);
        HEX(d4, 4); HEX(d5, 5); HEX(d6, 6);
#undef HEX

#pragma unroll
        for (int m = 1; m <= 8; m <<= 1) {
            a0 += __shfl_xor(a0, m, 64);
            a1 += __shfl_xor(a1, m, 64);
            a2 += __shfl_xor(a2, m, 64);
            a3 += __shfl_xor(a3, m, 64);
        }

        const int cur = it & 1;
        if (t < 4) {
            const float av = (t == 0) ? a0 : (t == 1) ? a1 : (t == 2) ? a2 : a3;
            const float bv = (t == 0) ? bias0 : (t == 1) ? bias1 : (t == 2) ? bias2 : bias3;
            const float v = av + bv;
            ((float*)&hbuf[cur][g])[t] = v > 0.f ? v : 0.f;
        }
        __syncthreads();

        // ---- FC: thread tid = output column, coalesced WfT reads ----
        const float4 w0 = WfT[(2 * it) * 256 + tid];
        const float4 w1 = WfT[(2 * it + 1) * 256 + tid];
#pragma unroll
        for (int g2 = 0; g2 < 16; ++g2) {
            const float4 hv = hbuf[cur][g2];
            const float4 w  = (g2 & 1) ? w1 : w0;
            acc2[g2 >> 1] += DOT(hv, w);
        }
    }

    const float bfv = bf[tid];
    const size_t outBase = (size_t)b0 * D_OUT + tid;
#pragma unroll
    for (int r2 = 0; r2 < RB; ++r2)
        out[outBase + (size_t)r2 * D_OUT] = acc2[r2] + bfv;
}

extern "C" void kernel_launch(void* const* d_in, const int* in_sizes, int n_in,
                              void* d_out, int out_size, void* d_ws, size_t ws_size,
                              hipStream_t stream) {
    const float* x  = (const float*)d_in[0];
    const float* nb = (const float*)d_in[1];
    const float* Wc = (const float*)d_in[2];
    const float* bc = (const float*)d_in[3];
    const float* Wd = (const float*)d_in[4];
    const float* bd = (const float*)d_in[5];
    const float* Wf = (const float*)d_in[6];
    const float* bf = (const float*)d_in[7];
    float* out = (float*)d_out;

    const int B = 16384;
    float4* WfT = (float4*)d_ws;   // 221184 B in preallocated scratch

    transpose_wf_kernel<<<dim3(N_POS), dim3(256), 0, stream>>>(Wf, WfT);

    dim3 grid(B / RB), block(THREADS);
    hexconv_fc_kernel<<<grid, block, 0, stream>>>(
        x, nb, Wc, bc, Wd, bd, bf, WfT, out);
}